// Round 8
// baseline (87.439 us; speedup 1.0000x reference)
//
#include <hip/hip_runtime.h>
#include <math.h>

#define CDIM 1024
#define RDIM 100
#define NBAGS 8192

typedef float floatx4 __attribute__((ext_vector_type(4)));
typedef short bf16x8 __attribute__((ext_vector_type(8)));

__device__ __forceinline__ float dot4(float4 a, float4 b) {
    return a.x * b.x + a.y * b.y + a.z * b.z + a.w * b.w;
}

// fp32 -> bf16 round-to-nearest-even
__device__ __forceinline__ unsigned short f2bf(float f) {
    unsigned int u = __builtin_bit_cast(unsigned int, f);
    u += 0x7FFFu + ((u >> 16) & 1u);
    return (unsigned short)(u >> 16);
}

// Kernel 1 (UNCHANGED from round 6/7): one BLOCK (4 waves) per bag, rows
// striped across waves, per-wave online-softmax state in registers, LDS merge.
// Blocks >= NBAGS convert W rows to bf16 for kernel 2.
__global__ __launch_bounds__(256) void bag_softmax_kernel(
    const float* __restrict__ X,
    const float* __restrict__ Constraints,
    const int* __restrict__ scope,
    const int* __restrict__ rel,
    const float* __restrict__ W,
    unsigned short* __restrict__ bagbuf,
    unsigned short* __restrict__ Wbf)
{
    const int lane = threadIdx.x & 63;
    const int w    = threadIdx.x >> 6;

    if (blockIdx.x >= NBAGS) {
        const int rr = blockIdx.x - NBAGS;
        const int t  = threadIdx.x;
        float4 v = *(const float4*)(W + (size_t)rr * CDIM + t * 4);
        ushort4 o;
        o.x = f2bf(v.x); o.y = f2bf(v.y); o.z = f2bf(v.z); o.w = f2bf(v.w);
        *(ushort4*)(Wbf + (size_t)rr * CDIM + t * 4) = o;
        return;
    }

    __shared__ float4 lds_acc[4][256];
    __shared__ float  lds_m[4];
    __shared__ float  lds_d[4];

    const int bag = blockIdx.x;
    const int s = scope[2 * bag];
    const int e = scope[2 * bag + 1];
    const int r = rel[bag];

    const float4* conp = (const float4*)(Constraints + (size_t)r * CDIM);
    const float4 c0 = conp[lane];
    const float4 c1 = conp[lane + 64];
    const float4 c2 = conp[lane + 128];
    const float4 c3 = conp[lane + 192];

    float4 a0 = {0.f, 0.f, 0.f, 0.f};
    float4 a1 = {0.f, 0.f, 0.f, 0.f};
    float4 a2 = {0.f, 0.f, 0.f, 0.f};
    float4 a3 = {0.f, 0.f, 0.f, 0.f};
    float m = -INFINITY;
    float denom = 0.f;

    int row = s + w;
    if (row < e) {                    // uniform per wave
        const float4* xp = (const float4*)(X + (size_t)row * CDIM);
        float4 A0 = xp[lane];
        float4 A1 = xp[lane + 64];
        float4 A2 = xp[lane + 128];
        float4 A3 = xp[lane + 192];

        for (; row < e; row += 4) {
            const int nxt = (row + 4 < e) ? (row + 4) : row;
            const float4* np = (const float4*)(X + (size_t)nxt * CDIM);
            float4 B0 = np[lane];
            float4 B1 = np[lane + 64];
            float4 B2 = np[lane + 128];
            float4 B3 = np[lane + 192];
            __builtin_amdgcn_sched_barrier(0);

            float p = dot4(A0, c0) + dot4(A1, c1) + dot4(A2, c2) + dot4(A3, c3);
            p += __shfl_xor(p, 1);
            p += __shfl_xor(p, 2);
            p += __shfl_xor(p, 4);
            p += __shfl_xor(p, 8);
            p += __shfl_xor(p, 16);
            p += __shfl_xor(p, 32);

            const float newm = fmaxf(m, p);
            const float corr = __expf(m - newm);   // 0 on first row
            const float wgt  = __expf(p - newm);
            denom = fmaf(denom, corr, wgt);
            a0.x = fmaf(a0.x, corr, wgt * A0.x); a0.y = fmaf(a0.y, corr, wgt * A0.y);
            a0.z = fmaf(a0.z, corr, wgt * A0.z); a0.w = fmaf(a0.w, corr, wgt * A0.w);
            a1.x = fmaf(a1.x, corr, wgt * A1.x); a1.y = fmaf(a1.y, corr, wgt * A1.y);
            a1.z = fmaf(a1.z, corr, wgt * A1.z); a1.w = fmaf(a1.w, corr, wgt * A1.w);
            a2.x = fmaf(a2.x, corr, wgt * A2.x); a2.y = fmaf(a2.y, corr, wgt * A2.y);
            a2.z = fmaf(a2.z, corr, wgt * A2.z); a2.w = fmaf(a2.w, corr, wgt * A2.w);
            a3.x = fmaf(a3.x, corr, wgt * A3.x); a3.y = fmaf(a3.y, corr, wgt * A3.y);
            a3.z = fmaf(a3.z, corr, wgt * A3.z); a3.w = fmaf(a3.w, corr, wgt * A3.w);
            m = newm;

            A0 = B0; A1 = B1; A2 = B2; A3 = B3;
        }
    }

    if (lane == 0) { lds_m[w] = m; lds_d[w] = denom; }
    lds_acc[w][lane]       = a0;
    lds_acc[w][lane + 64]  = a1;
    lds_acc[w][lane + 128] = a2;
    lds_acc[w][lane + 192] = a3;
    __syncthreads();

    const int t = threadIdx.x;
    const float m0 = lds_m[0], m1 = lds_m[1], m2 = lds_m[2], m3 = lds_m[3];
    const float ms = fmaxf(fmaxf(m0, m1), fmaxf(m2, m3));
    const float f0 = __expf(m0 - ms);
    const float f1 = __expf(m1 - ms);
    const float f2 = __expf(m2 - ms);
    const float f3 = __expf(m3 - ms);
    const float dn = f0 * lds_d[0] + f1 * lds_d[1] + f2 * lds_d[2] + f3 * lds_d[3];
    const float inv = 1.0f / dn;

    const float4 v0 = lds_acc[0][t];
    const float4 v1 = lds_acc[1][t];
    const float4 v2 = lds_acc[2][t];
    const float4 v3 = lds_acc[3][t];
    const float ox = (f0 * v0.x + f1 * v1.x + f2 * v2.x + f3 * v3.x) * inv;
    const float oy = (f0 * v0.y + f1 * v1.y + f2 * v2.y + f3 * v3.y) * inv;
    const float oz = (f0 * v0.z + f1 * v1.z + f2 * v2.z + f3 * v3.z) * inv;
    const float ow = (f0 * v0.w + f1 * v1.w + f2 * v2.w + f3 * v3.w) * inv;

    ushort4 o;
    o.x = f2bf(ox); o.y = f2bf(oy); o.z = f2bf(oz); o.w = f2bf(ow);
    *(ushort4*)(bagbuf + (size_t)bag * CDIM + t * 4) = o;
}

// Kernel 2 (UNCHANGED from round 7): MFMA GEMM with split-K x4.
__global__ __launch_bounds__(256) void bag_gemm_mfma(
    const unsigned short* __restrict__ bagbuf,
    const unsigned short* __restrict__ Wbf,
    const float* __restrict__ bias,
    float* __restrict__ out)
{
    const int q    = threadIdx.x >> 6;   // k-chunk 0..3
    const int lane = threadIdx.x & 63;
    const int bag0 = blockIdx.x * 16;
    const int ln15 = lane & 15;
    const int koff = (lane >> 4) * 8;

    __shared__ floatx4 lds[4][7][64];    // 28 KB

    floatx4 acc[7];
    #pragma unroll
    for (int t = 0; t < 7; ++t) acc[t] = (floatx4){0.f, 0.f, 0.f, 0.f};

    const unsigned short* aRow = bagbuf + (size_t)(bag0 + ln15) * CDIM + koff;

    #pragma unroll
    for (int i = 0; i < 8; ++i) {
        const int k0 = (q * 8 + i) * 32;
        const bf16x8 a = *(const bf16x8*)(aRow + k0);

        #pragma unroll
        for (int t = 0; t < 7; ++t) {
            const int r = t * 16 + ln15;
            bf16x8 b = (bf16x8)0;
            if (r < RDIM) {
                b = *(const bf16x8*)(Wbf + (size_t)r * CDIM + k0 + koff);
            }
            acc[t] = __builtin_amdgcn_mfma_f32_16x16x32_bf16(a, b, acc[t], 0, 0, 0);
        }
    }

    #pragma unroll
    for (int t = 0; t < 7; ++t) lds[q][t][lane] = acc[t];
    __syncthreads();

    #pragma unroll
    for (int p = threadIdx.x; p < 448; p += 256) {
        const int t    = p >> 6;
        const int slot = p & 63;
        const int r    = t * 16 + (slot & 15);
        if (r < RDIM) {
            floatx4 s = lds[0][t][slot];
            s += lds[1][t][slot];
            s += lds[2][t][slot];
            s += lds[3][t][slot];
            const float bv = bias[r];
            const int bagr = bag0 + (slot >> 4) * 4;
            out[(size_t)(bagr + 0) * RDIM + r] = s[0] + bv;
            out[(size_t)(bagr + 1) * RDIM + r] = s[1] + bv;
            out[(size_t)(bagr + 2) * RDIM + r] = s[2] + bv;
            out[(size_t)(bagr + 3) * RDIM + r] = s[3] + bv;
        }
    }
}

extern "C" void kernel_launch(void* const* d_in, const int* in_sizes, int n_in,
                              void* d_out, int out_size, void* d_ws, size_t ws_size,
                              hipStream_t stream) {
    const float* X    = (const float*)d_in[0];
    const float* Con  = (const float*)d_in[1];
    const float* W    = (const float*)d_in[2];
    const float* bias = (const float*)d_in[3];
    const int* scope  = (const int*)d_in[4];
    const int* rel    = (const int*)d_in[5];
    float* out = (float*)d_out;

    unsigned short* bagbuf = (unsigned short*)d_ws;          // 8192*1024*2 = 16.8 MB
    unsigned short* Wbf    = bagbuf + (size_t)NBAGS * CDIM;  // 100*1024*2  = 0.2 MB

    bag_softmax_kernel<<<NBAGS + RDIM, 256, 0, stream>>>(X, Con, scope, rel, W, bagbuf, Wbf);
    // MEASUREMENT PROBE: k2 launched twice (idempotent, identical output).
    // dur_us(this round) - dur_us(round 7) = k2 duration (L3-warm estimate).
    bag_gemm_mfma<<<NBAGS / 16, 256, 0, stream>>>(bagbuf, Wbf, bias, out);
    bag_gemm_mfma<<<NBAGS / 16, 256, 0, stream>>>(bagbuf, Wbf, bias, out);
}

// Round 9
// 77.612 us; speedup vs baseline: 1.1266x; 1.1266x over previous
//
#include <hip/hip_runtime.h>
#include <math.h>

#define CDIM 1024
#define RDIM 100
#define NBAGS 8192
#define RPAD 112   // 7 r-tiles of 16

typedef float floatx4 __attribute__((ext_vector_type(4)));
typedef short bf16x8 __attribute__((ext_vector_type(8)));

__device__ __forceinline__ float dot4(float4 a, float4 b) {
    return a.x * b.x + a.y * b.y + a.z * b.z + a.w * b.w;
}

// fp32 -> bf16 round-to-nearest-even
__device__ __forceinline__ unsigned short f2bf(float f) {
    unsigned int u = __builtin_bit_cast(unsigned int, f);
    u += 0x7FFFu + ((u >> 16) & 1u);
    return (unsigned short)(u >> 16);
}

// Fragment layouts (bf16, element index):
//   PA[((T*32 + kc)*64 + lane)*8 + i] = bag[T*16 + (lane&15)][kc*32 + (lane>>4)*8 + i]
//   PW[((kc*7 + t)*64 + lane)*8 + i]  = W  [t*16  + (lane&15)][kc*32 + (lane>>4)*8 + i]
// -> every A/B fragment load in the GEMM is one contiguous 1 KB wave load.

// Kernel 1: one BLOCK (4 waves) per bag (unchanged math); epilogue now writes
// the PA fragment layout. Blocks >= NBAGS build PW (zero-padded rows 100-111).
__global__ __launch_bounds__(256) void bag_softmax_kernel(
    const float* __restrict__ X,
    const float* __restrict__ Constraints,
    const int* __restrict__ scope,
    const int* __restrict__ rel,
    const float* __restrict__ W,
    unsigned short* __restrict__ PA,
    unsigned short* __restrict__ PW)
{
    const int lane = threadIdx.x & 63;
    const int w    = threadIdx.x >> 6;

    if (blockIdx.x >= NBAGS) {
        // Build PW: one r-row per block (112 blocks), 4 channels per thread.
        const int rr = blockIdx.x - NBAGS;          // 0..111
        const int t  = threadIdx.x;                 // channels c = 4t..4t+3
        const int kc  = t >> 3;
        const int sub = (t >> 1) & 3;
        const int i0  = (t & 1) * 4;
        ushort4 o = {0, 0, 0, 0};
        if (rr < RDIM) {
            float4 v = *(const float4*)(W + (size_t)rr * CDIM + t * 4);
            o.x = f2bf(v.x); o.y = f2bf(v.y); o.z = f2bf(v.z); o.w = f2bf(v.w);
        }
        const int tt = rr >> 4, rl = rr & 15;
        *(ushort4*)(PW + ((size_t)(kc * 7 + tt) * 64 + sub * 16 + rl) * 8 + i0) = o;
        return;
    }

    __shared__ float4 lds_acc[4][256];
    __shared__ float  lds_m[4];
    __shared__ float  lds_d[4];

    const int bag = blockIdx.x;
    const int s = scope[2 * bag];
    const int e = scope[2 * bag + 1];
    const int r = rel[bag];

    const float4* conp = (const float4*)(Constraints + (size_t)r * CDIM);
    const float4 c0 = conp[lane];
    const float4 c1 = conp[lane + 64];
    const float4 c2 = conp[lane + 128];
    const float4 c3 = conp[lane + 192];

    float4 a0 = {0.f, 0.f, 0.f, 0.f};
    float4 a1 = {0.f, 0.f, 0.f, 0.f};
    float4 a2 = {0.f, 0.f, 0.f, 0.f};
    float4 a3 = {0.f, 0.f, 0.f, 0.f};
    float m = -INFINITY;
    float denom = 0.f;

    int row = s + w;
    if (row < e) {                    // uniform per wave
        const float4* xp = (const float4*)(X + (size_t)row * CDIM);
        float4 A0 = xp[lane];
        float4 A1 = xp[lane + 64];
        float4 A2 = xp[lane + 128];
        float4 A3 = xp[lane + 192];

        for (; row < e; row += 4) {
            const int nxt = (row + 4 < e) ? (row + 4) : row;
            const float4* np = (const float4*)(X + (size_t)nxt * CDIM);
            float4 B0 = np[lane];
            float4 B1 = np[lane + 64];
            float4 B2 = np[lane + 128];
            float4 B3 = np[lane + 192];
            __builtin_amdgcn_sched_barrier(0);

            float p = dot4(A0, c0) + dot4(A1, c1) + dot4(A2, c2) + dot4(A3, c3);
            p += __shfl_xor(p, 1);
            p += __shfl_xor(p, 2);
            p += __shfl_xor(p, 4);
            p += __shfl_xor(p, 8);
            p += __shfl_xor(p, 16);
            p += __shfl_xor(p, 32);

            const float newm = fmaxf(m, p);
            const float corr = __expf(m - newm);   // 0 on first row
            const float wgt  = __expf(p - newm);
            denom = fmaf(denom, corr, wgt);
            a0.x = fmaf(a0.x, corr, wgt * A0.x); a0.y = fmaf(a0.y, corr, wgt * A0.y);
            a0.z = fmaf(a0.z, corr, wgt * A0.z); a0.w = fmaf(a0.w, corr, wgt * A0.w);
            a1.x = fmaf(a1.x, corr, wgt * A1.x); a1.y = fmaf(a1.y, corr, wgt * A1.y);
            a1.z = fmaf(a1.z, corr, wgt * A1.z); a1.w = fmaf(a1.w, corr, wgt * A1.w);
            a2.x = fmaf(a2.x, corr, wgt * A2.x); a2.y = fmaf(a2.y, corr, wgt * A2.y);
            a2.z = fmaf(a2.z, corr, wgt * A2.z); a2.w = fmaf(a2.w, corr, wgt * A2.w);
            a3.x = fmaf(a3.x, corr, wgt * A3.x); a3.y = fmaf(a3.y, corr, wgt * A3.y);
            a3.z = fmaf(a3.z, corr, wgt * A3.z); a3.w = fmaf(a3.w, corr, wgt * A3.w);
            m = newm;

            A0 = B0; A1 = B1; A2 = B2; A3 = B3;
        }
    }

    if (lane == 0) { lds_m[w] = m; lds_d[w] = denom; }
    lds_acc[w][lane]       = a0;
    lds_acc[w][lane + 64]  = a1;
    lds_acc[w][lane + 128] = a2;
    lds_acc[w][lane + 192] = a3;
    __syncthreads();

    const int t = threadIdx.x;
    const float m0 = lds_m[0], m1 = lds_m[1], m2 = lds_m[2], m3 = lds_m[3];
    const float ms = fmaxf(fmaxf(m0, m1), fmaxf(m2, m3));
    const float f0 = __expf(m0 - ms);
    const float f1 = __expf(m1 - ms);
    const float f2 = __expf(m2 - ms);
    const float f3 = __expf(m3 - ms);
    const float dn = f0 * lds_d[0] + f1 * lds_d[1] + f2 * lds_d[2] + f3 * lds_d[3];
    const float inv = 1.0f / dn;

    const float4 v0 = lds_acc[0][t];
    const float4 v1 = lds_acc[1][t];
    const float4 v2 = lds_acc[2][t];
    const float4 v3 = lds_acc[3][t];
    const float ox = (f0 * v0.x + f1 * v1.x + f2 * v2.x + f3 * v3.x) * inv;
    const float oy = (f0 * v0.y + f1 * v1.y + f2 * v2.y + f3 * v3.y) * inv;
    const float oz = (f0 * v0.z + f1 * v1.z + f2 * v2.z + f3 * v3.z) * inv;
    const float ow = (f0 * v0.w + f1 * v1.w + f2 * v2.w + f3 * v3.w) * inv;

    ushort4 o;
    o.x = f2bf(ox); o.y = f2bf(oy); o.z = f2bf(oz); o.w = f2bf(ow);

    // PA fragment-layout store: channels c = 4t..4t+3.
    const int T   = bag >> 4, bl = bag & 15;
    const int kc  = t >> 3;
    const int sub = (t >> 1) & 3;
    const int i0  = (t & 1) * 4;
    *(ushort4*)(PA + ((size_t)(T * 32 + kc) * 64 + sub * 16 + bl) * 8 + i0) = o;
}

// Kernel 2: MFMA GEMM, all operands in fragment order (every load = one
// contiguous 1 KB wave load). Block = 32 bags, 8 waves: wave w -> k-chunk
// q=w>>1 (K=256), m-half h=w&1 (16 bags). Partials reduced through LDS.
__global__ __launch_bounds__(512) void bag_gemm_mfma(
    const unsigned short* __restrict__ PA,
    const unsigned short* __restrict__ PW,
    const float* __restrict__ bias,
    float* __restrict__ out)
{
    const int w    = threadIdx.x >> 6;   // 0..7
    const int q    = w >> 1;             // k-chunk
    const int h    = w & 1;              // m-half
    const int lane = threadIdx.x & 63;
    const int T    = blockIdx.x * 2 + h; // 16-bag tile id

    __shared__ floatx4 lds[8][7][64];    // 57 KB

    floatx4 acc[7];
    #pragma unroll
    for (int t = 0; t < 7; ++t) acc[t] = (floatx4){0.f, 0.f, 0.f, 0.f};

    const unsigned short* aBase = PA + ((size_t)T * 32 + q * 8) * 512 + lane * 8;
    const unsigned short* bBase = PW + (size_t)q * 56 * 512 + lane * 8;

    #pragma unroll
    for (int i = 0; i < 8; ++i) {
        const bf16x8 a = *(const bf16x8*)(aBase + i * 512);
        #pragma unroll
        for (int t = 0; t < 7; ++t) {
            const bf16x8 b = *(const bf16x8*)(bBase + (i * 7 + t) * 512);
            acc[t] = __builtin_amdgcn_mfma_f32_16x16x32_bf16(a, b, acc[t], 0, 0, 0);
        }
    }

    #pragma unroll
    for (int t = 0; t < 7; ++t) lds[w][t][lane] = acc[t];
    __syncthreads();

    // 2 m-halves x 7 tiles x 64 slots = 896 outputs of 4 bags each.
    #pragma unroll
    for (int p = threadIdx.x; p < 896; p += 512) {
        const int h2   = (p >= 448) ? 1 : 0;
        const int pp   = p - h2 * 448;
        const int t    = pp >> 6;
        const int slot = pp & 63;
        const int r    = t * 16 + (slot & 15);
        if (r < RDIM) {
            floatx4 s = lds[0 + h2][t][slot];
            s += lds[2 + h2][t][slot];
            s += lds[4 + h2][t][slot];
            s += lds[6 + h2][t][slot];
            const float bv = bias[r];
            const int bagr = blockIdx.x * 32 + h2 * 16 + (slot >> 4) * 4;
            out[(size_t)(bagr + 0) * RDIM + r] = s[0] + bv;
            out[(size_t)(bagr + 1) * RDIM + r] = s[1] + bv;
            out[(size_t)(bagr + 2) * RDIM + r] = s[2] + bv;
            out[(size_t)(bagr + 3) * RDIM + r] = s[3] + bv;
        }
    }
}

extern "C" void kernel_launch(void* const* d_in, const int* in_sizes, int n_in,
                              void* d_out, int out_size, void* d_ws, size_t ws_size,
                              hipStream_t stream) {
    const float* X    = (const float*)d_in[0];
    const float* Con  = (const float*)d_in[1];
    const float* W    = (const float*)d_in[2];
    const float* bias = (const float*)d_in[3];
    const int* scope  = (const int*)d_in[4];
    const int* rel    = (const int*)d_in[5];
    float* out = (float*)d_out;

    unsigned short* PA = (unsigned short*)d_ws;            // 8192*1024*2 = 16.8 MB
    unsigned short* PW = PA + (size_t)NBAGS * CDIM;        // 112*1024*2  = 0.23 MB

    bag_softmax_kernel<<<NBAGS + RPAD, 256, 0, stream>>>(X, Con, scope, rel, W, PA, PW);
    bag_gemm_mfma<<<NBAGS / 32, 512, 0, stream>>>(PA, PW, bias, out);
}

// Round 10
// 64.805 us; speedup vs baseline: 1.3493x; 1.1976x over previous
//
#include <hip/hip_runtime.h>
#include <math.h>

#define CDIM 1024
#define RDIM 100
#define NBAGS 8192
#define RPAD 112   // 7 r-tiles of 16

typedef float floatx4 __attribute__((ext_vector_type(4)));
typedef short bf16x8 __attribute__((ext_vector_type(8)));

__device__ __forceinline__ float dot4(float4 a, float4 b) {
    return a.x * b.x + a.y * b.y + a.z * b.z + a.w * b.w;
}

// fp32 -> bf16 round-to-nearest-even
__device__ __forceinline__ unsigned short f2bf(float f) {
    unsigned int u = __builtin_bit_cast(unsigned int, f);
    u += 0x7FFFu + ((u >> 16) & 1u);
    return (unsigned short)(u >> 16);
}

// PW fragment layout (bf16):
//   PW[((kc*7 + t)*64 + lane)*8 + i] = W[t*16 + (lane&15)][kc*32 + (lane>>4)*8 + i]
// (zero-padded rows 100..111) -> every B-fragment load is one contiguous 1 KB
// wave load and the GEMM inner loop is branch-free.
// bagbuf stays ROW-MAJOR: round-9 showed a fragment-ordered A-layout forces
// 16B-per-256B scatter writes in k1 (partial-line, ~4x write amplification).

// Kernel 1 (= round 7): one BLOCK (4 waves) per bag, rows striped across
// waves, per-wave online-softmax state in registers, LDS merge, coalesced
// row-major bf16 epilogue. Blocks >= NBAGS build PW.
__global__ __launch_bounds__(256) void bag_softmax_kernel(
    const float* __restrict__ X,
    const float* __restrict__ Constraints,
    const int* __restrict__ scope,
    const int* __restrict__ rel,
    const float* __restrict__ W,
    unsigned short* __restrict__ bagbuf,
    unsigned short* __restrict__ PW)
{
    const int lane = threadIdx.x & 63;
    const int w    = threadIdx.x >> 6;

    if (blockIdx.x >= NBAGS) {
        // Build PW: one r-row per block (112 blocks), 4 channels per thread.
        const int rr = blockIdx.x - NBAGS;          // 0..111
        const int t  = threadIdx.x;                 // channels c = 4t..4t+3
        const int kc  = t >> 3;
        const int sub = (t >> 1) & 3;
        const int i0  = (t & 1) * 4;
        ushort4 o = {0, 0, 0, 0};
        if (rr < RDIM) {
            float4 v = *(const float4*)(W + (size_t)rr * CDIM + t * 4);
            o.x = f2bf(v.x); o.y = f2bf(v.y); o.z = f2bf(v.z); o.w = f2bf(v.w);
        }
        const int tt = rr >> 4, rl = rr & 15;
        *(ushort4*)(PW + ((size_t)(kc * 7 + tt) * 64 + sub * 16 + rl) * 8 + i0) = o;
        return;
    }

    __shared__ float4 lds_acc[4][256];
    __shared__ float  lds_m[4];
    __shared__ float  lds_d[4];

    const int bag = blockIdx.x;
    const int s = scope[2 * bag];
    const int e = scope[2 * bag + 1];
    const int r = rel[bag];

    const float4* conp = (const float4*)(Constraints + (size_t)r * CDIM);
    const float4 c0 = conp[lane];
    const float4 c1 = conp[lane + 64];
    const float4 c2 = conp[lane + 128];
    const float4 c3 = conp[lane + 192];

    float4 a0 = {0.f, 0.f, 0.f, 0.f};
    float4 a1 = {0.f, 0.f, 0.f, 0.f};
    float4 a2 = {0.f, 0.f, 0.f, 0.f};
    float4 a3 = {0.f, 0.f, 0.f, 0.f};
    float m = -INFINITY;
    float denom = 0.f;

    int row = s + w;
    if (row < e) {                    // uniform per wave
        const float4* xp = (const float4*)(X + (size_t)row * CDIM);
        float4 A0 = xp[lane];
        float4 A1 = xp[lane + 64];
        float4 A2 = xp[lane + 128];
        float4 A3 = xp[lane + 192];

        for (; row < e; row += 4) {
            const int nxt = (row + 4 < e) ? (row + 4) : row;
            const float4* np = (const float4*)(X + (size_t)nxt * CDIM);
            float4 B0 = np[lane];
            float4 B1 = np[lane + 64];
            float4 B2 = np[lane + 128];
            float4 B3 = np[lane + 192];
            __builtin_amdgcn_sched_barrier(0);

            float p = dot4(A0, c0) + dot4(A1, c1) + dot4(A2, c2) + dot4(A3, c3);
            p += __shfl_xor(p, 1);
            p += __shfl_xor(p, 2);
            p += __shfl_xor(p, 4);
            p += __shfl_xor(p, 8);
            p += __shfl_xor(p, 16);
            p += __shfl_xor(p, 32);

            const float newm = fmaxf(m, p);
            const float corr = __expf(m - newm);   // 0 on first row
            const float wgt  = __expf(p - newm);
            denom = fmaf(denom, corr, wgt);
            a0.x = fmaf(a0.x, corr, wgt * A0.x); a0.y = fmaf(a0.y, corr, wgt * A0.y);
            a0.z = fmaf(a0.z, corr, wgt * A0.z); a0.w = fmaf(a0.w, corr, wgt * A0.w);
            a1.x = fmaf(a1.x, corr, wgt * A1.x); a1.y = fmaf(a1.y, corr, wgt * A1.y);
            a1.z = fmaf(a1.z, corr, wgt * A1.z); a1.w = fmaf(a1.w, corr, wgt * A1.w);
            a2.x = fmaf(a2.x, corr, wgt * A2.x); a2.y = fmaf(a2.y, corr, wgt * A2.y);
            a2.z = fmaf(a2.z, corr, wgt * A2.z); a2.w = fmaf(a2.w, corr, wgt * A2.w);
            a3.x = fmaf(a3.x, corr, wgt * A3.x); a3.y = fmaf(a3.y, corr, wgt * A3.y);
            a3.z = fmaf(a3.z, corr, wgt * A3.z); a3.w = fmaf(a3.w, corr, wgt * A3.w);
            m = newm;

            A0 = B0; A1 = B1; A2 = B2; A3 = B3;
        }
    }

    if (lane == 0) { lds_m[w] = m; lds_d[w] = denom; }
    lds_acc[w][lane]       = a0;
    lds_acc[w][lane + 64]  = a1;
    lds_acc[w][lane + 128] = a2;
    lds_acc[w][lane + 192] = a3;
    __syncthreads();

    const int t = threadIdx.x;
    const float m0 = lds_m[0], m1 = lds_m[1], m2 = lds_m[2], m3 = lds_m[3];
    const float ms = fmaxf(fmaxf(m0, m1), fmaxf(m2, m3));
    const float f0 = __expf(m0 - ms);
    const float f1 = __expf(m1 - ms);
    const float f2 = __expf(m2 - ms);
    const float f3 = __expf(m3 - ms);
    const float dn = f0 * lds_d[0] + f1 * lds_d[1] + f2 * lds_d[2] + f3 * lds_d[3];
    const float inv = 1.0f / dn;

    const float4 v0 = lds_acc[0][t];
    const float4 v1 = lds_acc[1][t];
    const float4 v2 = lds_acc[2][t];
    const float4 v3 = lds_acc[3][t];
    const float ox = (f0 * v0.x + f1 * v1.x + f2 * v2.x + f3 * v3.x) * inv;
    const float oy = (f0 * v0.y + f1 * v1.y + f2 * v2.y + f3 * v3.y) * inv;
    const float oz = (f0 * v0.z + f1 * v1.z + f2 * v2.z + f3 * v3.z) * inv;
    const float ow = (f0 * v0.w + f1 * v1.w + f2 * v2.w + f3 * v3.w) * inv;

    ushort4 o;
    o.x = f2bf(ox); o.y = f2bf(oy); o.z = f2bf(oz); o.w = f2bf(ow);
    *(ushort4*)(bagbuf + (size_t)bag * CDIM + t * 4) = o;   // coalesced
}

// Kernel 2: MFMA GEMM. A gathered from row-major bagbuf (16 full lines per
// wave-load, read-once traffic), B from packed PW (contiguous 1 KB wave
// loads, branch-free). Block = 32 bags, 8 waves: wave w -> k-chunk q=w>>1
// (K=256), m-half h=w&1 (16 bags). Partials reduced through LDS.
__global__ __launch_bounds__(512) void bag_gemm_mfma(
    const unsigned short* __restrict__ bagbuf,
    const unsigned short* __restrict__ PW,
    const float* __restrict__ bias,
    float* __restrict__ out)
{
    const int w    = threadIdx.x >> 6;   // 0..7
    const int q    = w >> 1;             // k-chunk
    const int h    = w & 1;              // m-half
    const int lane = threadIdx.x & 63;
    const int T    = blockIdx.x * 2 + h; // 16-bag tile id
    const int bag0 = T * 16;
    const int ln15 = lane & 15;
    const int koff = (lane >> 4) * 8;

    __shared__ floatx4 lds[8][7][64];    // 57 KB

    floatx4 acc[7];
    #pragma unroll
    for (int t = 0; t < 7; ++t) acc[t] = (floatx4){0.f, 0.f, 0.f, 0.f};

    const unsigned short* aRow  = bagbuf + (size_t)(bag0 + ln15) * CDIM + koff;
    const unsigned short* bBase = PW + (size_t)q * 56 * 512 + lane * 8;

    #pragma unroll
    for (int i = 0; i < 8; ++i) {
        const int k0 = (q * 8 + i) * 32;
        const bf16x8 a = *(const bf16x8*)(aRow + k0);
        #pragma unroll
        for (int t = 0; t < 7; ++t) {
            const bf16x8 b = *(const bf16x8*)(bBase + (i * 7 + t) * 512);
            acc[t] = __builtin_amdgcn_mfma_f32_16x16x32_bf16(a, b, acc[t], 0, 0, 0);
        }
    }

    #pragma unroll
    for (int t = 0; t < 7; ++t) lds[w][t][lane] = acc[t];
    __syncthreads();

    // 2 m-halves x 7 tiles x 64 slots = 896 outputs of 4 bags each.
    #pragma unroll
    for (int p = threadIdx.x; p < 896; p += 512) {
        const int h2   = (p >= 448) ? 1 : 0;
        const int pp   = p - h2 * 448;
        const int t    = pp >> 6;
        const int slot = pp & 63;
        const int r    = t * 16 + (slot & 15);
        if (r < RDIM) {
            floatx4 s = lds[0 + h2][t][slot];
            s += lds[2 + h2][t][slot];
            s += lds[4 + h2][t][slot];
            s += lds[6 + h2][t][slot];
            const float bv = bias[r];
            const int bagr = blockIdx.x * 32 + h2 * 16 + (slot >> 4) * 4;
            out[(size_t)(bagr + 0) * RDIM + r] = s[0] + bv;
            out[(size_t)(bagr + 1) * RDIM + r] = s[1] + bv;
            out[(size_t)(bagr + 2) * RDIM + r] = s[2] + bv;
            out[(size_t)(bagr + 3) * RDIM + r] = s[3] + bv;
        }
    }
}

extern "C" void kernel_launch(void* const* d_in, const int* in_sizes, int n_in,
                              void* d_out, int out_size, void* d_ws, size_t ws_size,
                              hipStream_t stream) {
    const float* X    = (const float*)d_in[0];
    const float* Con  = (const float*)d_in[1];
    const float* W    = (const float*)d_in[2];
    const float* bias = (const float*)d_in[3];
    const int* scope  = (const int*)d_in[4];
    const int* rel    = (const int*)d_in[5];
    float* out = (float*)d_out;

    unsigned short* bagbuf = (unsigned short*)d_ws;          // 8192*1024*2 = 16.8 MB
    unsigned short* PW     = bagbuf + (size_t)NBAGS * CDIM;  // 112*1024*2  = 0.23 MB

    bag_softmax_kernel<<<NBAGS + RPAD, 256, 0, stream>>>(X, Con, scope, rel, W, bagbuf, PW);
    bag_gemm_mfma<<<NBAGS / 32, 512, 0, stream>>>(bagbuf, PW, bias, out);
}

// Round 11
// 64.202 us; speedup vs baseline: 1.3619x; 1.0094x over previous
//
#include <hip/hip_runtime.h>
#include <math.h>

#define CDIM 1024
#define RDIM 100
#define NBAGS 8192
#define RPAD 112   // 7 r-tiles of 16

typedef float floatx4 __attribute__((ext_vector_type(4)));
typedef short bf16x8 __attribute__((ext_vector_type(8)));

__device__ __forceinline__ float dot4(float4 a, float4 b) {
    return a.x * b.x + a.y * b.y + a.z * b.z + a.w * b.w;
}

// fp32 -> bf16 round-to-nearest-even
__device__ __forceinline__ unsigned short f2bf(float f) {
    unsigned int u = __builtin_bit_cast(unsigned int, f);
    u += 0x7FFFu + ((u >> 16) & 1u);
    return (unsigned short)(u >> 16);
}

// Online-softmax update with one row held in registers (all rows real).
#define COMPUTE_ROW(A0, A1, A2, A3)                                          \
    {                                                                        \
        float p = dot4(A0, c0) + dot4(A1, c1) + dot4(A2, c2) + dot4(A3, c3); \
        p += __shfl_xor(p, 1);                                               \
        p += __shfl_xor(p, 2);                                               \
        p += __shfl_xor(p, 4);                                               \
        p += __shfl_xor(p, 8);                                               \
        p += __shfl_xor(p, 16);                                              \
        p += __shfl_xor(p, 32);                                              \
        const float newm = fmaxf(m, p);                                      \
        const float corr = __expf(m - newm);  /* 0 on first row */           \
        const float wgt  = __expf(p - newm);                                 \
        denom = fmaf(denom, corr, wgt);                                      \
        a0.x = fmaf(a0.x, corr, wgt * A0.x); a0.y = fmaf(a0.y, corr, wgt * A0.y); \
        a0.z = fmaf(a0.z, corr, wgt * A0.z); a0.w = fmaf(a0.w, corr, wgt * A0.w); \
        a1.x = fmaf(a1.x, corr, wgt * A1.x); a1.y = fmaf(a1.y, corr, wgt * A1.y); \
        a1.z = fmaf(a1.z, corr, wgt * A1.z); a1.w = fmaf(a1.w, corr, wgt * A1.w); \
        a2.x = fmaf(a2.x, corr, wgt * A2.x); a2.y = fmaf(a2.y, corr, wgt * A2.y); \
        a2.z = fmaf(a2.z, corr, wgt * A2.z); a2.w = fmaf(a2.w, corr, wgt * A2.w); \
        a3.x = fmaf(a3.x, corr, wgt * A3.x); a3.y = fmaf(a3.y, corr, wgt * A3.y); \
        a3.z = fmaf(a3.z, corr, wgt * A3.z); a3.w = fmaf(a3.w, corr, wgt * A3.w); \
        m = newm;                                                            \
    }

// Kernel 1: one BLOCK (4 waves) per bag, rows striped across waves (stride 4),
// per-wave online-softmax state in registers, LDS merge, coalesced row-major
// bf16 epilogue. Round-11 change: the row loop is PEELED — the main loop only
// runs while a successor chunk exists (prefetch is always a real row, vmcnt
// stays precise), and the last chunk's compute is peeled with no loads. This
// removes the clamped re-read prefetch (~131 MB of dead L1/L2 traffic; with
// avg 2 iters/wave, HALF of all iterations issued 4 dead 1 KB loads that also
// had to drain before the merge barrier). Blocks >= NBAGS build PW.
__global__ __launch_bounds__(256) void bag_softmax_kernel(
    const float* __restrict__ X,
    const float* __restrict__ Constraints,
    const int* __restrict__ scope,
    const int* __restrict__ rel,
    const float* __restrict__ W,
    unsigned short* __restrict__ bagbuf,
    unsigned short* __restrict__ PW)
{
    const int lane = threadIdx.x & 63;
    const int w    = threadIdx.x >> 6;

    if (blockIdx.x >= NBAGS) {
        // Build PW: one r-row per block (112 blocks), 4 channels per thread.
        // PW[((kc*7+t)*64 + lane)*8 + i] = W[t*16+(lane&15)][kc*32+(lane>>4)*8+i]
        const int rr = blockIdx.x - NBAGS;          // 0..111
        const int t  = threadIdx.x;                 // channels c = 4t..4t+3
        const int kc  = t >> 3;
        const int sub = (t >> 1) & 3;
        const int i0  = (t & 1) * 4;
        ushort4 o = {0, 0, 0, 0};
        if (rr < RDIM) {
            float4 v = *(const float4*)(W + (size_t)rr * CDIM + t * 4);
            o.x = f2bf(v.x); o.y = f2bf(v.y); o.z = f2bf(v.z); o.w = f2bf(v.w);
        }
        const int tt = rr >> 4, rl = rr & 15;
        *(ushort4*)(PW + ((size_t)(kc * 7 + tt) * 64 + sub * 16 + rl) * 8 + i0) = o;
        return;
    }

    __shared__ float4 lds_acc[4][256];
    __shared__ float  lds_m[4];
    __shared__ float  lds_d[4];

    const int bag = blockIdx.x;
    const int s = scope[2 * bag];
    const int e = scope[2 * bag + 1];
    const int r = rel[bag];

    const float4* conp = (const float4*)(Constraints + (size_t)r * CDIM);
    const float4 c0 = conp[lane];
    const float4 c1 = conp[lane + 64];
    const float4 c2 = conp[lane + 128];
    const float4 c3 = conp[lane + 192];

    float4 a0 = {0.f, 0.f, 0.f, 0.f};
    float4 a1 = {0.f, 0.f, 0.f, 0.f};
    float4 a2 = {0.f, 0.f, 0.f, 0.f};
    float4 a3 = {0.f, 0.f, 0.f, 0.f};
    float m = -INFINITY;
    float denom = 0.f;

    int row = s + w;
    if (row < e) {                    // uniform per wave
        const float4* xp = (const float4*)(X + (size_t)row * CDIM);
        float4 A0 = xp[lane];
        float4 A1 = xp[lane + 64];
        float4 A2 = xp[lane + 128];
        float4 A3 = xp[lane + 192];

        // main loop: only iterations with a real successor chunk
        for (; row + 4 < e; row += 4) {
            const float4* np = (const float4*)(X + (size_t)(row + 4) * CDIM);
            float4 B0 = np[lane];
            float4 B1 = np[lane + 64];
            float4 B2 = np[lane + 128];
            float4 B3 = np[lane + 192];
            __builtin_amdgcn_sched_barrier(0);

            COMPUTE_ROW(A0, A1, A2, A3)

            A0 = B0; A1 = B1; A2 = B2; A3 = B3;
        }
        // peeled final chunk: compute only, zero loads
        COMPUTE_ROW(A0, A1, A2, A3)
    }

    if (lane == 0) { lds_m[w] = m; lds_d[w] = denom; }
    lds_acc[w][lane]       = a0;
    lds_acc[w][lane + 64]  = a1;
    lds_acc[w][lane + 128] = a2;
    lds_acc[w][lane + 192] = a3;
    __syncthreads();

    const int t = threadIdx.x;
    const float m0 = lds_m[0], m1 = lds_m[1], m2 = lds_m[2], m3 = lds_m[3];
    const float ms = fmaxf(fmaxf(m0, m1), fmaxf(m2, m3));
    const float f0 = __expf(m0 - ms);   // idle wave: exp(-inf) = 0
    const float f1 = __expf(m1 - ms);
    const float f2 = __expf(m2 - ms);
    const float f3 = __expf(m3 - ms);
    const float dn = f0 * lds_d[0] + f1 * lds_d[1] + f2 * lds_d[2] + f3 * lds_d[3];
    const float inv = 1.0f / dn;

    const float4 v0 = lds_acc[0][t];
    const float4 v1 = lds_acc[1][t];
    const float4 v2 = lds_acc[2][t];
    const float4 v3 = lds_acc[3][t];
    const float ox = (f0 * v0.x + f1 * v1.x + f2 * v2.x + f3 * v3.x) * inv;
    const float oy = (f0 * v0.y + f1 * v1.y + f2 * v2.y + f3 * v3.y) * inv;
    const float oz = (f0 * v0.z + f1 * v1.z + f2 * v2.z + f3 * v3.z) * inv;
    const float ow = (f0 * v0.w + f1 * v1.w + f2 * v2.w + f3 * v3.w) * inv;

    ushort4 o;
    o.x = f2bf(ox); o.y = f2bf(oy); o.z = f2bf(oz); o.w = f2bf(ow);
    *(ushort4*)(bagbuf + (size_t)bag * CDIM + t * 4) = o;   // coalesced
}

// Kernel 2 (UNCHANGED from round 10): MFMA GEMM. A gathered from row-major
// bagbuf, B from packed PW (contiguous 1 KB wave loads, branch-free).
// Block = 32 bags, 8 waves: wave w -> k-chunk q=w>>1, m-half h=w&1.
__global__ __launch_bounds__(512) void bag_gemm_mfma(
    const unsigned short* __restrict__ bagbuf,
    const unsigned short* __restrict__ PW,
    const float* __restrict__ bias,
    float* __restrict__ out)
{
    const int w    = threadIdx.x >> 6;   // 0..7
    const int q    = w >> 1;             // k-chunk
    const int h    = w & 1;              // m-half
    const int lane = threadIdx.x & 63;
    const int T    = blockIdx.x * 2 + h; // 16-bag tile id
    const int bag0 = T * 16;
    const int ln15 = lane & 15;
    const int koff = (lane >> 4) * 8;

    __shared__ floatx4 lds[8][7][64];    // 57 KB

    floatx4 acc[7];
    #pragma unroll
    for (int t = 0; t < 7; ++t) acc[t] = (floatx4){0.f, 0.f, 0.f, 0.f};

    const unsigned short* aRow  = bagbuf + (size_t)(bag0 + ln15) * CDIM + koff;
    const unsigned short* bBase = PW + (size_t)q * 56 * 512 + lane * 8;

    #pragma unroll
    for (int i = 0; i < 8; ++i) {
        const int k0 = (q * 8 + i) * 32;
        const bf16x8 a = *(const bf16x8*)(aRow + k0);
        #pragma unroll
        for (int t = 0; t < 7; ++t) {
            const bf16x8 b = *(const bf16x8*)(bBase + (i * 7 + t) * 512);
            acc[t] = __builtin_amdgcn_mfma_f32_16x16x32_bf16(a, b, acc[t], 0, 0, 0);
        }
    }

    #pragma unroll
    for (int t = 0; t < 7; ++t) lds[w][t][lane] = acc[t];
    __syncthreads();

    // 2 m-halves x 7 tiles x 64 slots = 896 outputs of 4 bags each.
    #pragma unroll
    for (int p = threadIdx.x; p < 896; p += 512) {
        const int h2   = (p >= 448) ? 1 : 0;
        const int pp   = p - h2 * 448;
        const int t    = pp >> 6;
        const int slot = pp & 63;
        const int r    = t * 16 + (slot & 15);
        if (r < RDIM) {
            floatx4 s = lds[0 + h2][t][slot];
            s += lds[2 + h2][t][slot];
            s += lds[4 + h2][t][slot];
            s += lds[6 + h2][t][slot];
            const float bv = bias[r];
            const int bagr = blockIdx.x * 32 + h2 * 16 + (slot >> 4) * 4;
            out[(size_t)(bagr + 0) * RDIM + r] = s[0] + bv;
            out[(size_t)(bagr + 1) * RDIM + r] = s[1] + bv;
            out[(size_t)(bagr + 2) * RDIM + r] = s[2] + bv;
            out[(size_t)(bagr + 3) * RDIM + r] = s[3] + bv;
        }
    }
}

extern "C" void kernel_launch(void* const* d_in, const int* in_sizes, int n_in,
                              void* d_out, int out_size, void* d_ws, size_t ws_size,
                              hipStream_t stream) {
    const float* X    = (const float*)d_in[0];
    const float* Con  = (const float*)d_in[1];
    const float* W    = (const float*)d_in[2];
    const float* bias = (const float*)d_in[3];
    const int* scope  = (const int*)d_in[4];
    const int* rel    = (const int*)d_in[5];
    float* out = (float*)d_out;

    unsigned short* bagbuf = (unsigned short*)d_ws;          // 8192*1024*2 = 16.8 MB
    unsigned short* PW     = bagbuf + (size_t)NBAGS * CDIM;  // 112*1024*2  = 0.23 MB

    bag_softmax_kernel<<<NBAGS + RPAD, 256, 0, stream>>>(X, Con, scope, rel, W, bagbuf, PW);
    bag_gemm_mfma<<<NBAGS / 32, 512, 0, stream>>>(bagbuf, PW, bias, out);
}

// Round 12
// 63.798 us; speedup vs baseline: 1.3706x; 1.0063x over previous
//
#include <hip/hip_runtime.h>
#include <math.h>

#define CDIM 1024
#define RDIM 100
#define NBAGS 8192
#define RPAD 112   // 7 r-tiles of 16

typedef float floatx4 __attribute__((ext_vector_type(4)));
typedef short bf16x8 __attribute__((ext_vector_type(8)));

__device__ __forceinline__ float dot4(float4 a, float4 b) {
    return a.x * b.x + a.y * b.y + a.z * b.z + a.w * b.w;
}

// fp32 -> bf16 round-to-nearest-even
__device__ __forceinline__ unsigned short f2bf(float f) {
    unsigned int u = __builtin_bit_cast(unsigned int, f);
    u += 0x7FFFu + ((u >> 16) & 1u);
    return (unsigned short)(u >> 16);
}

#define LOADROW(D0, D1, D2, D3, ri)                                          \
    {                                                                        \
        const float4* p_ = (const float4*)(X + (size_t)(ri) * CDIM);         \
        D0 = p_[lane];       D1 = p_[lane + 64];                             \
        D2 = p_[lane + 128]; D3 = p_[lane + 192];                            \
    }

// Online-softmax update with one row held in named registers.
#define COMPUTE_ROW(A0, A1, A2, A3)                                          \
    {                                                                        \
        float p = dot4(A0, c0) + dot4(A1, c1) + dot4(A2, c2) + dot4(A3, c3); \
        p += __shfl_xor(p, 1);                                               \
        p += __shfl_xor(p, 2);                                               \
        p += __shfl_xor(p, 4);                                               \
        p += __shfl_xor(p, 8);                                               \
        p += __shfl_xor(p, 16);                                              \
        p += __shfl_xor(p, 32);                                              \
        const float newm = fmaxf(m, p);                                      \
        const float corr = __expf(m - newm);  /* 0 on first row */           \
        const float wgt  = __expf(p - newm);                                 \
        denom = fmaf(denom, corr, wgt);                                      \
        a0.x = fmaf(a0.x, corr, wgt * A0.x); a0.y = fmaf(a0.y, corr, wgt * A0.y); \
        a0.z = fmaf(a0.z, corr, wgt * A0.z); a0.w = fmaf(a0.w, corr, wgt * A0.w); \
        a1.x = fmaf(a1.x, corr, wgt * A1.x); a1.y = fmaf(a1.y, corr, wgt * A1.y); \
        a1.z = fmaf(a1.z, corr, wgt * A1.z); a1.w = fmaf(a1.w, corr, wgt * A1.w); \
        a2.x = fmaf(a2.x, corr, wgt * A2.x); a2.y = fmaf(a2.y, corr, wgt * A2.y); \
        a2.z = fmaf(a2.z, corr, wgt * A2.z); a2.w = fmaf(a2.w, corr, wgt * A2.w); \
        a3.x = fmaf(a3.x, corr, wgt * A3.x); a3.y = fmaf(a3.y, corr, wgt * A3.y); \
        a3.z = fmaf(a3.z, corr, wgt * A3.z); a3.w = fmaf(a3.w, corr, wgt * A3.w); \
        m = newm;                                                            \
    }

// Kernel 1: one BLOCK (4 waves) per bag, rows striped across waves (stride 4),
// per-wave online-softmax state in registers, LDS merge, coalesced row-major
// bf16 epilogue. Round-12 change: 2-DEEP register prefetch (A/B/C) — one row
// of HBM latency (~900cy) exceeds the ~400cy compute chain, so 1-deep leaves
// ~500cy/iter exposed; this mattered for the ~72-row straggler bags whose
// late-dispatched blocks extend the kernel tail. Blocks >= NBAGS build PW.
__global__ __launch_bounds__(256) void bag_softmax_kernel(
    const float* __restrict__ X,
    const float* __restrict__ Constraints,
    const int* __restrict__ scope,
    const int* __restrict__ rel,
    const float* __restrict__ W,
    unsigned short* __restrict__ bagbuf,
    unsigned short* __restrict__ PW)
{
    const int lane = threadIdx.x & 63;
    const int w    = threadIdx.x >> 6;

    if (blockIdx.x >= NBAGS) {
        // Build PW: one r-row per block (112 blocks), 4 channels per thread.
        // PW[((kc*7+t)*64 + lane)*8 + i] = W[t*16+(lane&15)][kc*32+(lane>>4)*8+i]
        const int rr = blockIdx.x - NBAGS;          // 0..111
        const int t  = threadIdx.x;                 // channels c = 4t..4t+3
        const int kc  = t >> 3;
        const int sub = (t >> 1) & 3;
        const int i0  = (t & 1) * 4;
        ushort4 o = {0, 0, 0, 0};
        if (rr < RDIM) {
            float4 v = *(const float4*)(W + (size_t)rr * CDIM + t * 4);
            o.x = f2bf(v.x); o.y = f2bf(v.y); o.z = f2bf(v.z); o.w = f2bf(v.w);
        }
        const int tt = rr >> 4, rl = rr & 15;
        *(ushort4*)(PW + ((size_t)(kc * 7 + tt) * 64 + sub * 16 + rl) * 8 + i0) = o;
        return;
    }

    __shared__ float4 lds_acc[4][256];
    __shared__ float  lds_m[4];
    __shared__ float  lds_d[4];

    const int bag = blockIdx.x;
    const int s = scope[2 * bag];
    const int e = scope[2 * bag + 1];
    const int r = rel[bag];

    const float4* conp = (const float4*)(Constraints + (size_t)r * CDIM);
    const float4 c0 = conp[lane];
    const float4 c1 = conp[lane + 64];
    const float4 c2 = conp[lane + 128];
    const float4 c3 = conp[lane + 192];

    float4 a0 = {0.f, 0.f, 0.f, 0.f};
    float4 a1 = {0.f, 0.f, 0.f, 0.f};
    float4 a2 = {0.f, 0.f, 0.f, 0.f};
    float4 a3 = {0.f, 0.f, 0.f, 0.f};
    float m = -INFINITY;
    float denom = 0.f;

    int row = s + w;
    if (row < e) {                    // uniform per wave
        float4 A0, A1, A2, A3;        // row
        float4 B0, B1, B2, B3;        // row+4
        float4 C0, C1, C2, C3;        // row+8 (rotating)

        LOADROW(A0, A1, A2, A3, row)
        if (row + 4 < e) LOADROW(B0, B1, B2, B3, row + 4)

        // main loop: runs only while row+8 is a real row (2-deep prefetch)
        for (; row + 8 < e; row += 4) {
            LOADROW(C0, C1, C2, C3, row + 8)
            __builtin_amdgcn_sched_barrier(0);
            COMPUTE_ROW(A0, A1, A2, A3)
            A0 = B0; A1 = B1; A2 = B2; A3 = B3;
            B0 = C0; B1 = C1; B2 = C2; B3 = C3;
        }
        // epilogue: 1 or 2 rows left in registers, zero loads
        if (row + 4 < e) {
            COMPUTE_ROW(A0, A1, A2, A3)
            COMPUTE_ROW(B0, B1, B2, B3)
        } else {
            COMPUTE_ROW(A0, A1, A2, A3)
        }
    }

    if (lane == 0) { lds_m[w] = m; lds_d[w] = denom; }
    lds_acc[w][lane]       = a0;
    lds_acc[w][lane + 64]  = a1;
    lds_acc[w][lane + 128] = a2;
    lds_acc[w][lane + 192] = a3;
    __syncthreads();

    const int t = threadIdx.x;
    const float m0 = lds_m[0], m1 = lds_m[1], m2 = lds_m[2], m3 = lds_m[3];
    const float ms = fmaxf(fmaxf(m0, m1), fmaxf(m2, m3));
    const float f0 = __expf(m0 - ms);   // idle wave: exp(-inf) = 0
    const float f1 = __expf(m1 - ms);
    const float f2 = __expf(m2 - ms);
    const float f3 = __expf(m3 - ms);
    const float dn = f0 * lds_d[0] + f1 * lds_d[1] + f2 * lds_d[2] + f3 * lds_d[3];
    const float inv = 1.0f / dn;

    const float4 v0 = lds_acc[0][t];
    const float4 v1 = lds_acc[1][t];
    const float4 v2 = lds_acc[2][t];
    const float4 v3 = lds_acc[3][t];
    const float ox = (f0 * v0.x + f1 * v1.x + f2 * v2.x + f3 * v3.x) * inv;
    const float oy = (f0 * v0.y + f1 * v1.y + f2 * v2.y + f3 * v3.y) * inv;
    const float oz = (f0 * v0.z + f1 * v1.z + f2 * v2.z + f3 * v3.z) * inv;
    const float ow = (f0 * v0.w + f1 * v1.w + f2 * v2.w + f3 * v3.w) * inv;

    ushort4 o;
    o.x = f2bf(ox); o.y = f2bf(oy); o.z = f2bf(oz); o.w = f2bf(ow);
    *(ushort4*)(bagbuf + (size_t)bag * CDIM + t * 4) = o;   // coalesced
}

// Kernel 2: MFMA GEMM, round-12 change: 8-way K-split. Block = 16 bags,
// 8 waves, wave q owns K-chunk [q*128, q*128+128) (4 kc-iters x 7 MFMA).
// 512 blocks x 512 threads = 4096 waves (was 2048) halves the serial body
// and doubles latency-hiding for this short, latency-bound kernel.
// A gathered from row-major bagbuf; B from packed PW (1 KB coalesced loads).
__global__ __launch_bounds__(512) void bag_gemm_mfma(
    const unsigned short* __restrict__ bagbuf,
    const unsigned short* __restrict__ PW,
    const float* __restrict__ bias,
    float* __restrict__ out)
{
    const int q    = threadIdx.x >> 6;   // k-chunk 0..7
    const int lane = threadIdx.x & 63;
    const int bag0 = blockIdx.x * 16;
    const int ln15 = lane & 15;
    const int koff = (lane >> 4) * 8;

    __shared__ floatx4 lds[8][7][64];    // 57 KB

    floatx4 acc[7];
    #pragma unroll
    for (int t = 0; t < 7; ++t) acc[t] = (floatx4){0.f, 0.f, 0.f, 0.f};

    const unsigned short* aRow  = bagbuf + (size_t)(bag0 + ln15) * CDIM + koff;
    const unsigned short* bBase = PW + lane * 8;

    #pragma unroll
    for (int i = 0; i < 4; ++i) {
        const int kc = q * 4 + i;
        const bf16x8 a = *(const bf16x8*)(aRow + kc * 32);
        #pragma unroll
        for (int t = 0; t < 7; ++t) {
            const bf16x8 b = *(const bf16x8*)(bBase + (size_t)(kc * 7 + t) * 512);
            acc[t] = __builtin_amdgcn_mfma_f32_16x16x32_bf16(a, b, acc[t], 0, 0, 0);
        }
    }

    #pragma unroll
    for (int t = 0; t < 7; ++t) lds[q][t][lane] = acc[t];
    __syncthreads();

    // 7 tiles x 64 slots = 448 outputs of 4 bags each, over 512 threads.
    const int p = threadIdx.x;
    if (p < 448) {
        const int t    = p >> 6;
        const int slot = p & 63;
        const int r    = t * 16 + (slot & 15);
        if (r < RDIM) {
            floatx4 s = lds[0][t][slot];
            #pragma unroll
            for (int qq = 1; qq < 8; ++qq) s += lds[qq][t][slot];
            const float bv = bias[r];
            const int bagr = bag0 + (slot >> 4) * 4;
            out[(size_t)(bagr + 0) * RDIM + r] = s[0] + bv;
            out[(size_t)(bagr + 1) * RDIM + r] = s[1] + bv;
            out[(size_t)(bagr + 2) * RDIM + r] = s[2] + bv;
            out[(size_t)(bagr + 3) * RDIM + r] = s[3] + bv;
        }
    }
}

extern "C" void kernel_launch(void* const* d_in, const int* in_sizes, int n_in,
                              void* d_out, int out_size, void* d_ws, size_t ws_size,
                              hipStream_t stream) {
    const float* X    = (const float*)d_in[0];
    const float* Con  = (const float*)d_in[1];
    const float* W    = (const float*)d_in[2];
    const float* bias = (const float*)d_in[3];
    const int* scope  = (const int*)d_in[4];
    const int* rel    = (const int*)d_in[5];
    float* out = (float*)d_out;

    unsigned short* bagbuf = (unsigned short*)d_ws;          // 8192*1024*2 = 16.8 MB
    unsigned short* PW     = bagbuf + (size_t)NBAGS * CDIM;  // 112*1024*2  = 0.23 MB

    bag_softmax_kernel<<<NBAGS + RPAD, 256, 0, stream>>>(X, Con, scope, rel, W, bagbuf, PW);
    bag_gemm_mfma<<<NBAGS / 16, 512, 0, stream>>>(bagbuf, PW, bias, out);
}